// Round 18
// baseline (741.288 us; speedup 1.0000x reference)
//
#include <hip/hip_runtime.h>
#include <math.h>

#define EPSQ 1e-5f
#define TOK 8192
#define DM 2048
#define DF 8192
#define NW (DM*DF)
#define NGU 16384   // interleaved gate/up weight rows (32-row groups)

typedef float f32x4 __attribute__((ext_vector_type(4)));
typedef int   int32x4 __attribute__((ext_vector_type(4)));
typedef int   int32x16 __attribute__((ext_vector_type(16)));
typedef char  i8x4 __attribute__((ext_vector_type(4)));
typedef char  i8x8 __attribute__((ext_vector_type(8)));
typedef _Float16 f16x8 __attribute__((ext_vector_type(8)));

// ---- fixed workspace layout (bytes) ----
#define OFF_DSUM 0ull                                // 3 doubles
#define OFF_SX   (4ull<<10)                          // 8192 f32
#define OFF_SH   (40ull<<10)                         // 8192 f32
#define OFF_XQ   (1ull<<20)                          // 16MB i8 [8192][2048]
#define OFF_WCAT (OFF_XQ  + (16ull<<20))             // 32MB i8 [16384][2048] gate/up interleaved
#define OFF_WDQ  (OFF_WCAT + (32ull<<20))            // 16MB i8 [2048][8192]
#define OFF_HQ   (OFF_WDQ + (16ull<<20))             // 64MB i8 [8192][8192]
#define FIXED_END (OFF_HQ + (64ull<<20))             // 129MB
// strip region (after FIXED_END): h fp16 [S][8192]

#define GLL(gp, lp) __builtin_amdgcn_global_load_lds( \
    (const __attribute__((address_space(1))) unsigned int*)(gp), \
    (__attribute__((address_space(3))) unsigned int*)(lp), 16, 0, 0)

// ---- |w| sums for all three weights (absmean scales), f64 totals ----
__global__ void k_wabs3(const float* __restrict__ w0, const float* __restrict__ w1,
                        const float* __restrict__ w2, double* __restrict__ dsum, int n4) {
  const float* w = blockIdx.y == 0 ? w0 : blockIdx.y == 1 ? w1 : w2;
  const f32x4* w4 = (const f32x4*)w;
  float s = 0.f;
  for (int i = blockIdx.x * blockDim.x + threadIdx.x; i < n4; i += gridDim.x * blockDim.x) {
    f32x4 v = w4[i];
    s += fabsf(v.x) + fabsf(v.y) + fabsf(v.z) + fabsf(v.w);
  }
  __shared__ float red[256];
  red[threadIdx.x] = s; __syncthreads();
  for (int o = 128; o > 0; o >>= 1) {
    if (threadIdx.x < o) red[threadIdx.x] += red[threadIdx.x + o];
    __syncthreads();
  }
  if (threadIdx.x == 0) atomicAdd(dsum + blockIdx.y, (double)red[0]);
}

// ---- ternary-quantize weights -> int8 {-1,0,1}.
// gate/up (y=0/1) write INTERLEAVED 32-row groups into wq_gu:
//   src row r -> R = 64*(r/32) + 32*y + (r%32); down (y=2) writes plain wq_d.
__global__ void k_quant_w3(const float* __restrict__ w0, const float* __restrict__ w1,
                           const float* __restrict__ w2, char* __restrict__ wq_gu,
                           char* __restrict__ wq_d, const double* __restrict__ dsum, int n4) {
  const int y = blockIdx.y;
  const float* w = y == 0 ? w0 : y == 1 ? w1 : w2;
  float scale = (float)(dsum[y] / (double)NW) + EPSQ;
  const f32x4* w4 = (const f32x4*)w;
  for (int i = blockIdx.x * blockDim.x + threadIdx.x; i < n4; i += gridDim.x * blockDim.x) {
    f32x4 v = w4[i];
    i8x4 o;
#pragma unroll
    for (int c = 0; c < 4; c++) {
      float q = rintf(v[c] / scale);
      q = fminf(1.f, fmaxf(-1.f, q));
      o[c] = (char)(int)q;
    }
    if (y < 2) {
      const int r = i >> 9, c4 = i & 511;        // 512 x f32x4 chunks per 2048-row
      const int R = ((r & ~31) << 1) + (y << 5) + (r & 31);
      *(i8x4*)&wq_gu[((size_t)R * 512 + c4) * 4] = o;
    } else {
      *(i8x4*)&wq_d[(size_t)i * 4] = o;
    }
  }
}

// ---- per-token int8 quantize x -> int8 + scale ----
__global__ void k_quant_x(const float* __restrict__ x, char* __restrict__ xq,
                          float* __restrict__ sx) {
  const int row = blockIdx.x;
  const int tid = threadIdx.x;
  const f32x4* xr = (const f32x4*)(x + (size_t)row * DM);
  f32x4 v0 = xr[tid * 2], v1 = xr[tid * 2 + 1];
  float m = 0.f;
#pragma unroll
  for (int c = 0; c < 4; c++) m = fmaxf(m, fmaxf(fabsf(v0[c]), fabsf(v1[c])));
  __shared__ float red[256];
  red[tid] = m; __syncthreads();
  for (int o = 128; o > 0; o >>= 1) {
    if (tid < o) red[tid] = fmaxf(red[tid], red[tid + o]);
    __syncthreads();
  }
  float sc = fmaxf(red[0], EPSQ) / 127.f;
  if (tid == 0) sx[row] = sc;
  i8x8 o;
#pragma unroll
  for (int c = 0; c < 4; c++) {
    float q0 = fminf(127.f, fmaxf(-128.f, rintf(v0[c] / sc)));
    float q1 = fminf(127.f, fmaxf(-128.f, rintf(v1[c] / sc)));
    o[c] = (char)(int)q0; o[c + 4] = (char)(int)q1;
  }
  *(i8x8*)&xq[(size_t)row * DM + tid * 8] = o;
}

// ---- row max + int8 quantize of h (fp16) ----
__global__ void k_hquant(const _Float16* __restrict__ h, char* __restrict__ hq,
                         float* __restrict__ sh) {
  const int row = blockIdx.x;
  const int tid = threadIdx.x;
  const f16x8* h8 = (const f16x8*)(h + (size_t)row * DF);
  float hv[32];
  float m = 0.f;
#pragma unroll
  for (int j = 0; j < 4; j++) {
    f16x8 v = h8[tid * 4 + j];
#pragma unroll
    for (int c = 0; c < 8; c++) {
      float f = (float)v[c];
      hv[j * 8 + c] = f;
      m = fmaxf(m, fabsf(f));
    }
  }
  __shared__ float red[256];
  red[tid] = m; __syncthreads();
  for (int o = 128; o > 0; o >>= 1) {
    if (tid < o) red[tid] = fmaxf(red[tid], red[tid + o]);
    __syncthreads();
  }
  float sc = fmaxf(red[0], EPSQ) / 127.f;
  if (tid == 0) sh[row] = sc;
#pragma unroll
  for (int jj = 0; jj < 4; jj++) {
    i8x8 o;
#pragma unroll
    for (int c = 0; c < 8; c++) {
      float q = fminf(127.f, fmaxf(-128.f, rintf(hv[jj * 8 + c] / sc)));
      o[c] = (char)(int)q;
    }
    *(i8x8*)&hq[(size_t)row * DF + tid * 32 + jj * 8] = o;
  }
}

// ---- PERSISTENT 256x256-tile i8 MFMA GEMM, 32x32x32 MFMA (4404 vs 3944
//      TOPS µbench, half the instruction count). r17 schedule otherwise:
//      4-deep BK=64 ring, frag double-buffer, counted vmcnt 8/4/0, T2
//      swizzle via pre-swizzled GLL source, setprio+sched_group interleave,
//      persistent tile loop with next-prologue-before-epilogue, column-major
//      lid->(m,n) + XCD swizzle.
//      Per wave: 128x64 out = 4 m-tiles x 2 n-tiles of 32x32; per K=64
//      sub-tile 12 ds_read_b128 (conflict-free: 16-lane groups read 16
//      consecutive rows x XOR-swizzled slots, 2-way max) feed 16 MFMAs.
// FUSE=0: C[row*N+col] = acc * rowscale[row] * swA           (OT = float)
// FUSE=1: weight cols in 64-groups = 32 gate + 32 up; n-tile 0 = gate,
//         n-tile 1 = up of the SAME h-group -> same-lane pairing;
//         h[row*(N/2) + (n0+wn*64)/2 + (lane&31)] = sigmoid(g)*u  (fp16)
template<int FUSE, typename OT>
__global__ __launch_bounds__(512, 2)
void k_gemm8(const char* __restrict__ A, const char* __restrict__ B,
             OT* __restrict__ C, const float* __restrict__ rowscale,
             const double* __restrict__ dsumA, const double* __restrict__ dsumB,
             int M, int N, int K, int nv) {
  __shared__ __align__(16) char sm[4][2][16384];

  const int tid = threadIdx.x;
  const int wv = tid >> 6;
  const int lane = tid & 63;
  const int wm = wv >> 2;
  const int wn = wv & 3;
  const int row_l = lane & 31;      // row/col within 32x32 tile
  const int hi = lane >> 5;         // k-half selector
  const int key = (row_l >> 1) & 3; // read-side slot swizzle key

  const int b = blockIdx.x;
  const int lidr = (b & 7) * 32 + (b >> 3);   // XCD swizzle within a round of 256
  const int gy = M >> 8;
  const int T = nv >> 8;                      // tiles per block

  const float swA = (float)(*dsumA / (double)NW) + EPSQ;
  const float swB = (float)(*dsumB / (double)NW) + EPSQ;

  const int srow = lane >> 2;
  const int sslot = (lane & 3) ^ ((lane >> 3) & 3);
  const int dst0 = (wv * 32) * 64 + lane * 16;
  const int dst1 = dst0 + 1024;
  const int NS = K >> 6;

  const int arow = (wm * 128 + row_l) * 64;   // byte base in A plane
  const int brow = (wn * 64 + row_l) * 64;    // byte base in B plane
  const int sk0 = (hi ^ key) << 4;            // slot for ks=0
  const int sk1 = ((2 + hi) ^ key) << 4;      // slot for ks=1

  int m0 = 0, n0 = 0;
  const char *gA0 = nullptr, *gA1 = nullptr, *gB0 = nullptr, *gB1 = nullptr;

#define SETPTR(vt) do { \
    const int lid_ = (vt) * 256 + lidr; \
    m0 = (lid_ % gy) << 8; \
    n0 = (lid_ / gy) << 8; \
    gA0 = A + (size_t)(m0 + wv * 32 + srow) * K + sslot * 16; \
    gA1 = gA0 + (size_t)16 * K; \
    gB0 = B + (size_t)(n0 + wv * 32 + srow) * K + sslot * 16; \
    gB1 = gB0 + (size_t)16 * K; \
  } while (0)

#define STAGE(s) do { \
    const size_t ko_ = (size_t)(s) * 64; \
    char* pA_ = &sm[(s) & 3][0][0]; \
    char* pB_ = &sm[(s) & 3][1][0]; \
    GLL(gA0 + ko_, pA_ + dst0); \
    GLL(gA1 + ko_, pA_ + dst1); \
    GLL(gB0 + ko_, pB_ + dst0); \
    GLL(gB1 + ko_, pB_ + dst1); \
  } while (0)

#define READS(NA, NB, slot_) do { \
    const char* smA_ = &sm[(slot_)][0][0]; \
    const char* smB_ = &sm[(slot_)][1][0]; \
    _Pragma("unroll") \
    for (int nt = 0; nt < 2; nt++) { \
      NB[nt][0] = *(const int32x4*)&smB_[brow + nt * 2048 + sk0]; \
      NB[nt][1] = *(const int32x4*)&smB_[brow + nt * 2048 + sk1]; \
    } \
    _Pragma("unroll") \
    for (int mt = 0; mt < 4; mt++) { \
      NA[mt][0] = *(const int32x4*)&smA_[arow + mt * 2048 + sk0]; \
      NA[mt][1] = *(const int32x4*)&smA_[arow + mt * 2048 + sk1]; \
    } \
  } while (0)

#define MFMAS(CA, CB) do { \
    _Pragma("unroll") \
    for (int ks = 0; ks < 2; ks++) \
      _Pragma("unroll") \
      for (int mt = 0; mt < 4; mt++) \
        _Pragma("unroll") \
        for (int nt = 0; nt < 2; nt++) \
          acc[mt][nt] = __builtin_amdgcn_mfma_i32_32x32x32_i8( \
              CA[mt][ks], CB[nt][ks], acc[mt][nt], 0, 0, 0); \
  } while (0)

#define INTERLEAVE() do { \
    _Pragma("unroll") \
    for (int gg = 0; gg < 4; gg++) { \
      __builtin_amdgcn_sched_group_barrier(0x100, 3, 0); \
      __builtin_amdgcn_sched_group_barrier(0x008, 4, 0); \
    } \
  } while (0)

#define ITER(sv, CA, CB, NA, NB) do { \
    const int s_ = (sv); \
    const int ahead_ = NS - 1 - s_; \
    if (ahead_ >= 3) { \
      STAGE(s_ + 3); \
      asm volatile("s_waitcnt vmcnt(8)" ::: "memory"); \
    } else if (ahead_ == 2) { \
      asm volatile("s_waitcnt vmcnt(4)" ::: "memory"); \
    } else { \
      asm volatile("s_waitcnt vmcnt(0)" ::: "memory"); \
    } \
    asm volatile("s_waitcnt lgkmcnt(0)" ::: "memory"); \
    __builtin_amdgcn_sched_barrier(0); \
    __builtin_amdgcn_s_barrier(); \
    __builtin_amdgcn_s_setprio(1); \
    READS(NA, NB, (s_ + 1) & 3); \
    MFMAS(CA, CB); \
    INTERLEAVE(); \
    __builtin_amdgcn_s_setprio(0); \
  } while (0)

  int32x16 acc[4][2];
  const int32x16 z16 = {0};
  int32x4 curA[4][2], curB[2][2], nxtA[4][2], nxtB[2][2];

  SETPTR(0);
  STAGE(0); STAGE(1); STAGE(2);

  for (int vt = 0; vt < T; ++vt) {
    const int em0 = m0, en0 = n0;   // epilogue coords for THIS tile

#pragma unroll
    for (int mt = 0; mt < 4; mt++)
#pragma unroll
      for (int nt = 0; nt < 2; nt++) acc[mt][nt] = z16;

    asm volatile("s_waitcnt vmcnt(8)" ::: "memory");
    __builtin_amdgcn_s_barrier();
    READS(curA, curB, 0);

    for (int s = 0; s + 1 < NS - 1; s += 2) {
      ITER(s, curA, curB, nxtA, nxtB);
      ITER(s + 1, nxtA, nxtB, curA, curB);
    }
    ITER(NS - 2, curA, curB, nxtA, nxtB);

    asm volatile("s_waitcnt lgkmcnt(0)" ::: "memory");
    __builtin_amdgcn_sched_barrier(0);
    __builtin_amdgcn_s_setprio(1);
    MFMAS(nxtA, nxtB);
    __builtin_amdgcn_s_setprio(0);

    // issue NEXT tile's prologue stages before the epilogue (latency hiding)
    if (vt + 1 < T) {
      SETPTR(vt + 1);
      STAGE(0); STAGE(1); STAGE(2);
    }

    // epilogue: 32x32 C/D layout col = lane&31, row = (reg&3)+8*(reg>>2)+4*hi
    if constexpr (FUSE) {
      const int hb = (en0 + wn * 64) >> 1;
#pragma unroll
      for (int mt = 0; mt < 4; mt++) {
#pragma unroll
        for (int reg = 0; reg < 16; reg++) {
          const int row = em0 + wm * 128 + mt * 32 + (reg & 3) + ((reg >> 2) << 3) + (hi << 2);
          const float rs = rowscale[row];
          const float gv = (float)acc[mt][0][reg] * rs * swA;
          const float uv = (float)acc[mt][1][reg] * rs * swB;
          const float hv = uv / (1.f + exp2f(gv * -1.44269504f));
          C[(size_t)row * (N >> 1) + hb + row_l] = (OT)hv;
        }
      }
    } else {
#pragma unroll
      for (int mt = 0; mt < 4; mt++) {
#pragma unroll
        for (int reg = 0; reg < 16; reg++) {
          const int row = em0 + wm * 128 + mt * 32 + (reg & 3) + ((reg >> 2) << 3) + (hi << 2);
          const float rs = rowscale[row] * swA;
#pragma unroll
          for (int nt = 0; nt < 2; nt++) {
            const int col = en0 + wn * 64 + nt * 32 + row_l;
            C[(size_t)row * N + col] = (OT)((float)acc[mt][nt][reg] * rs);
          }
        }
      }
    }
  }
#undef ITER
#undef INTERLEAVE
#undef READS
#undef MFMAS
#undef STAGE
#undef SETPTR
}

extern "C" void kernel_launch(void* const* d_in, const int* in_sizes, int n_in,
                              void* d_out, int out_size, void* d_ws, size_t ws_size,
                              hipStream_t stream) {
  const float* x  = (const float*)d_in[0];
  const float* wg = (const float*)d_in[1];
  const float* wu = (const float*)d_in[2];
  const float* wd = (const float*)d_in[3];
  float* out = (float*)d_out;
  char* ws = (char*)d_ws;

  double* dsum = (double*)(ws + OFF_DSUM);
  float* sx = (float*)(ws + OFF_SX);
  float* sh = (float*)(ws + OFF_SH);
  char* xq   = ws + OFF_XQ;
  char* wcat = ws + OFF_WCAT;  // [16384][2048] gate/up interleaved (32-row groups)
  char* wdq  = ws + OFF_WDQ;
  char* hq   = ws + OFF_HQ;    // full [8192][8192] int8

  // strip sizing: per row need 8192*2 B (h fp16); S multiple of 256
  size_t avail = ws_size > FIXED_END ? ws_size - FIXED_END : 0;
  int S = 256;
  for (int cand = 8192; cand >= 256; cand >>= 1) {
    if ((size_t)cand * 16384ull <= avail) { S = cand; break; }
  }
  _Float16* hbuf = (_Float16*)(ws + FIXED_END);

  hipMemsetAsync(ws, 0, 64, stream);

  const int n4 = NW / 4;
  k_wabs3<<<dim3(2048, 3), 256, 0, stream>>>(wg, wu, wd, dsum, n4);
  k_quant_w3<<<dim3(2048, 3), 256, 0, stream>>>(wg, wu, wd, wcat, wdq, dsum, n4);
  k_quant_x<<<TOK, 256, 0, stream>>>(x, xq, sx);

  for (int base = 0; base < TOK; base += S) {
    // h = sigmoid(x@wg^T) * (x@wu^T) in one persistent GEMM over interleaved
    // w_cat (N = 16384 weight cols -> 8192 fp16 h cols per row)
    k_gemm8<1, _Float16><<<256, 512, 0, stream>>>(
        xq + (size_t)base * DM, wcat, hbuf, sx + base,
        dsum + 0, dsum + 1, S, NGU, DM, (S / 256) * (NGU / 256));

    k_hquant<<<S, 256, 0, stream>>>(hbuf, hq + (size_t)base * DF, sh + base);
  }

  // single persistent down-projection GEMM over all rows (fp32 out)
  k_gemm8<0, float><<<256, 512, 0, stream>>>(
      hq, wdq, out, sh, dsum + 2, dsum + 2, TOK, DM, DF,
      (TOK / 256) * (DM / 256));
}

// Round 19
// 619.910 us; speedup vs baseline: 1.1958x; 1.1958x over previous
//
#include <hip/hip_runtime.h>
#include <math.h>

#define EPSQ 1e-5f
#define TOK 8192
#define DM 2048
#define DF 8192
#define NW (DM*DF)
#define NGU 16384   // interleaved gate/up weight rows (16-row groups)

typedef float f32x4 __attribute__((ext_vector_type(4)));
typedef int   int32x4 __attribute__((ext_vector_type(4)));
typedef char  i8x4 __attribute__((ext_vector_type(4)));
typedef char  i8x8 __attribute__((ext_vector_type(8)));
typedef _Float16 f16x8 __attribute__((ext_vector_type(8)));

// ---- fixed workspace layout (bytes) ----
#define OFF_DSUM 0ull                                // 3 doubles
#define OFF_SX   (4ull<<10)                          // 8192 f32
#define OFF_SH   (40ull<<10)                         // 8192 f32
#define OFF_XQ   (1ull<<20)                          // 16MB i8 [8192][2048]
#define OFF_WCAT (OFF_XQ  + (16ull<<20))             // 32MB i8 [16384][2048] gate/up interleaved
#define OFF_WDQ  (OFF_WCAT + (32ull<<20))            // 16MB i8 [2048][8192]
#define OFF_HQ   (OFF_WDQ + (16ull<<20))             // 64MB i8 [8192][8192]
#define FIXED_END (OFF_HQ + (64ull<<20))             // 129MB
// strip region (after FIXED_END): h fp16 [S][8192]

#define GLL(gp, lp) __builtin_amdgcn_global_load_lds( \
    (const __attribute__((address_space(1))) unsigned int*)(gp), \
    (__attribute__((address_space(3))) unsigned int*)(lp), 16, 0, 0)

// ---- |w| sums for all three weights (absmean scales), f64 totals ----
__global__ void k_wabs3(const float* __restrict__ w0, const float* __restrict__ w1,
                        const float* __restrict__ w2, double* __restrict__ dsum, int n4) {
  const float* w = blockIdx.y == 0 ? w0 : blockIdx.y == 1 ? w1 : w2;
  const f32x4* w4 = (const f32x4*)w;
  float s = 0.f;
  for (int i = blockIdx.x * blockDim.x + threadIdx.x; i < n4; i += gridDim.x * blockDim.x) {
    f32x4 v = w4[i];
    s += fabsf(v.x) + fabsf(v.y) + fabsf(v.z) + fabsf(v.w);
  }
  __shared__ float red[256];
  red[threadIdx.x] = s; __syncthreads();
  for (int o = 128; o > 0; o >>= 1) {
    if (threadIdx.x < o) red[threadIdx.x] += red[threadIdx.x + o];
    __syncthreads();
  }
  if (threadIdx.x == 0) atomicAdd(dsum + blockIdx.y, (double)red[0]);
}

// ---- ternary-quantize weights -> int8 {-1,0,1}.
// gate/up (y=0/1) write INTERLEAVED 16-row groups into wq_gu:
//   src row r -> R = 32*(r/16) + 16*y + (r%16); down (y=2) writes plain wq_d.
__global__ void k_quant_w3(const float* __restrict__ w0, const float* __restrict__ w1,
                           const float* __restrict__ w2, char* __restrict__ wq_gu,
                           char* __restrict__ wq_d, const double* __restrict__ dsum, int n4) {
  const int y = blockIdx.y;
  const float* w = y == 0 ? w0 : y == 1 ? w1 : w2;
  float scale = (float)(dsum[y] / (double)NW) + EPSQ;
  const f32x4* w4 = (const f32x4*)w;
  for (int i = blockIdx.x * blockDim.x + threadIdx.x; i < n4; i += gridDim.x * blockDim.x) {
    f32x4 v = w4[i];
    i8x4 o;
#pragma unroll
    for (int c = 0; c < 4; c++) {
      float q = rintf(v[c] / scale);
      q = fminf(1.f, fmaxf(-1.f, q));
      o[c] = (char)(int)q;
    }
    if (y < 2) {
      const int r = i >> 9, c4 = i & 511;        // 512 x f32x4 chunks per 2048-row
      const int R = ((r & ~15) << 1) + (y << 4) + (r & 15);
      *(i8x4*)&wq_gu[((size_t)R * 512 + c4) * 4] = o;
    } else {
      *(i8x4*)&wq_d[(size_t)i * 4] = o;
    }
  }
}

// ---- per-token int8 quantize x -> int8 + scale ----
__global__ void k_quant_x(const float* __restrict__ x, char* __restrict__ xq,
                          float* __restrict__ sx) {
  const int row = blockIdx.x;
  const int tid = threadIdx.x;
  const f32x4* xr = (const f32x4*)(x + (size_t)row * DM);
  f32x4 v0 = xr[tid * 2], v1 = xr[tid * 2 + 1];
  float m = 0.f;
#pragma unroll
  for (int c = 0; c < 4; c++) m = fmaxf(m, fmaxf(fabsf(v0[c]), fabsf(v1[c])));
  __shared__ float red[256];
  red[tid] = m; __syncthreads();
  for (int o = 128; o > 0; o >>= 1) {
    if (tid < o) red[tid] = fmaxf(red[tid], red[tid + o]);
    __syncthreads();
  }
  float sc = fmaxf(red[0], EPSQ) / 127.f;
  if (tid == 0) sx[row] = sc;
  i8x8 o;
#pragma unroll
  for (int c = 0; c < 4; c++) {
    float q0 = fminf(127.f, fmaxf(-128.f, rintf(v0[c] / sc)));
    float q1 = fminf(127.f, fmaxf(-128.f, rintf(v1[c] / sc)));
    o[c] = (char)(int)q0; o[c + 4] = (char)(int)q1;
  }
  *(i8x8*)&xq[(size_t)row * DM + tid * 8] = o;
}

// ---- row max + int8 quantize of h (fp16) ----
__global__ void k_hquant(const _Float16* __restrict__ h, char* __restrict__ hq,
                         float* __restrict__ sh) {
  const int row = blockIdx.x;
  const int tid = threadIdx.x;
  const f16x8* h8 = (const f16x8*)(h + (size_t)row * DF);
  float hv[32];
  float m = 0.f;
#pragma unroll
  for (int j = 0; j < 4; j++) {
    f16x8 v = h8[tid * 4 + j];
#pragma unroll
    for (int c = 0; c < 8; c++) {
      float f = (float)v[c];
      hv[j * 8 + c] = f;
      m = fmaxf(m, fabsf(f));
    }
  }
  __shared__ float red[256];
  red[tid] = m; __syncthreads();
  for (int o = 128; o > 0; o >>= 1) {
    if (tid < o) red[tid] = fmaxf(red[tid], red[tid + o]);
    __syncthreads();
  }
  float sc = fmaxf(red[0], EPSQ) / 127.f;
  if (tid == 0) sh[row] = sc;
#pragma unroll
  for (int jj = 0; jj < 4; jj++) {
    i8x8 o;
#pragma unroll
    for (int c = 0; c < 8; c++) {
      float q = fminf(127.f, fmaxf(-128.f, rintf(hv[jj * 8 + c] / sc)));
      o[c] = (char)(int)q;
    }
    *(i8x8*)&hq[(size_t)row * DF + tid * 32 + jj * 8] = o;
  }
}

// ---- PERSISTENT 256x256-tile i8 MFMA GEMM (16x16x64 MFMA; r17 verified
//      best). 4-deep BK=64 ring, frag double-buffer, counted vmcnt 8/4/0,
//      T2 swizzle via pre-swizzled GLL source (conflict-free: 16-lane groups
//      cover all 8 bank-starts exactly 2x), setprio+sched_group interleave,
//      persistent tile loop with next-prologue-before-epilogue, column-major
//      lid->(m,n) + XCD swizzle.
// FUSE=0: C[row*N+col] = acc * rowscale[row] * swA           (OT = float)
// FUSE=1: weight cols are gate/up interleaved (16-col groups); epilogue
//         computes h = sigmoid(g)*u per pair and writes fp16 h at
//         h[row*(N/2) + (n0+wn*64)/2 + p*16 + lr]            (OT = _Float16)
template<int FUSE, typename OT>
__global__ __launch_bounds__(512, 2)
void k_gemm8(const char* __restrict__ A, const char* __restrict__ B,
             OT* __restrict__ C, const float* __restrict__ rowscale,
             const double* __restrict__ dsumA, const double* __restrict__ dsumB,
             int M, int N, int K, int nv) {
  __shared__ __align__(16) char sm[4][2][16384];

  const int tid = threadIdx.x;
  const int wv = tid >> 6;
  const int lane = tid & 63;
  const int wm = wv >> 2;
  const int wn = wv & 3;
  const int lr = lane & 15;
  const int g = lane >> 4;
  const int c3 = (lr >> 1) & 3;

  const int b = blockIdx.x;
  const int lidr = (b & 7) * 32 + (b >> 3);   // XCD swizzle within a round of 256
  const int gy = M >> 8;
  const int T = nv >> 8;                      // tiles per block

  const float swA = (float)(*dsumA / (double)NW) + EPSQ;
  const float swB = (float)(*dsumB / (double)NW) + EPSQ;

  const int srow = lane >> 2;
  const int sslot = (lane & 3) ^ ((lane >> 3) & 3);
  const int dst0 = (wv * 32) * 64 + lane * 16;
  const int dst1 = dst0 + 1024;
  const int NS = K >> 6;
  const int abase = (wm * 128 + lr) * 64 + ((g ^ c3) << 4);
  const int bbase = (wn * 64 + lr) * 64 + ((g ^ c3) << 4);

  int m0 = 0, n0 = 0;
  const char *gA0 = nullptr, *gA1 = nullptr, *gB0 = nullptr, *gB1 = nullptr;

#define SETPTR(vt) do { \
    const int lid_ = (vt) * 256 + lidr; \
    m0 = (lid_ % gy) << 8; \
    n0 = (lid_ / gy) << 8; \
    gA0 = A + (size_t)(m0 + wv * 32 + srow) * K + sslot * 16; \
    gA1 = gA0 + (size_t)16 * K; \
    gB0 = B + (size_t)(n0 + wv * 32 + srow) * K + sslot * 16; \
    gB1 = gB0 + (size_t)16 * K; \
  } while (0)

#define STAGE(s) do { \
    const size_t ko_ = (size_t)(s) * 64; \
    char* pA_ = &sm[(s) & 3][0][0]; \
    char* pB_ = &sm[(s) & 3][1][0]; \
    GLL(gA0 + ko_, pA_ + dst0); \
    GLL(gA1 + ko_, pA_ + dst1); \
    GLL(gB0 + ko_, pB_ + dst0); \
    GLL(gB1 + ko_, pB_ + dst1); \
  } while (0)

#define READS(NA, NB, slot_) do { \
    const char* smA_ = &sm[(slot_)][0][0]; \
    const char* smB_ = &sm[(slot_)][1][0]; \
    _Pragma("unroll") \
    for (int n = 0; n < 4; n++) NB[n] = *(const int32x4*)&smB_[bbase + n * 1024]; \
    _Pragma("unroll") \
    for (int m = 0; m < 8; m++) NA[m] = *(const int32x4*)&smA_[abase + m * 1024]; \
  } while (0)

#define MFMAS(CA, CB) do { \
    _Pragma("unroll") \
    for (int m = 0; m < 8; m++) \
      _Pragma("unroll") \
      for (int n = 0; n < 4; n++) \
        acc[m][n] = __builtin_amdgcn_mfma_i32_16x16x64_i8(CA[m], CB[n], acc[m][n], 0, 0, 0); \
  } while (0)

#define INTERLEAVE() do { \
    _Pragma("unroll") \
    for (int gg = 0; gg < 6; gg++) { \
      __builtin_amdgcn_sched_group_barrier(0x100, 2, 0); \
      __builtin_amdgcn_sched_group_barrier(0x008, 5, 0); \
    } \
    __builtin_amdgcn_sched_group_barrier(0x008, 2, 0); \
  } while (0)

#define ITER(sv, CA, CB, NA, NB) do { \
    const int s_ = (sv); \
    const int ahead_ = NS - 1 - s_; \
    if (ahead_ >= 3) { \
      STAGE(s_ + 3); \
      asm volatile("s_waitcnt vmcnt(8)" ::: "memory"); \
    } else if (ahead_ == 2) { \
      asm volatile("s_waitcnt vmcnt(4)" ::: "memory"); \
    } else { \
      asm volatile("s_waitcnt vmcnt(0)" ::: "memory"); \
    } \
    asm volatile("s_waitcnt lgkmcnt(0)" ::: "memory"); \
    __builtin_amdgcn_sched_barrier(0); \
    __builtin_amdgcn_s_barrier(); \
    __builtin_amdgcn_s_setprio(1); \
    READS(NA, NB, (s_ + 1) & 3); \
    MFMAS(CA, CB); \
    INTERLEAVE(); \
    __builtin_amdgcn_s_setprio(0); \
  } while (0)

  int32x4 acc[8][4];
  const int32x4 z4 = {0, 0, 0, 0};
  int32x4 curA[8], curB[4], nxtA[8], nxtB[4];

  SETPTR(0);
  STAGE(0); STAGE(1); STAGE(2);

  for (int vt = 0; vt < T; ++vt) {
    const int em0 = m0, en0 = n0;   // epilogue coords for THIS tile

#pragma unroll
    for (int m = 0; m < 8; m++)
#pragma unroll
      for (int n = 0; n < 4; n++) acc[m][n] = z4;

    asm volatile("s_waitcnt vmcnt(8)" ::: "memory");
    __builtin_amdgcn_s_barrier();
    READS(curA, curB, 0);

    for (int s = 0; s + 1 < NS - 1; s += 2) {
      ITER(s, curA, curB, nxtA, nxtB);
      ITER(s + 1, nxtA, nxtB, curA, curB);
    }
    ITER(NS - 2, curA, curB, nxtA, nxtB);

    asm volatile("s_waitcnt lgkmcnt(0)" ::: "memory");
    __builtin_amdgcn_sched_barrier(0);
    __builtin_amdgcn_s_setprio(1);
    MFMAS(nxtA, nxtB);
    __builtin_amdgcn_s_setprio(0);

    // issue NEXT tile's prologue stages before the epilogue (latency hiding).
    // LDS hazard audit: slots 0,1,2 last read >=1 barrier ago (lgkm-drained);
    // slot 3 (still in flight for final MFMAS regs) is untouched.
    if (vt + 1 < T) {
      SETPTR(vt + 1);
      STAGE(0); STAGE(1); STAGE(2);
    }

    // epilogue: C/D layout col = lane&15, row = (lane>>4)*4 + j
    if constexpr (FUSE) {
      const int hbase = (en0 + wn * 64) >> 1;
#pragma unroll
      for (int m = 0; m < 8; m++) {
#pragma unroll
        for (int j = 0; j < 4; j++) {
          const int row = em0 + wm * 128 + m * 16 + g * 4 + j;
          const float rs = rowscale[row];
#pragma unroll
          for (int p = 0; p < 2; p++) {
            const float gv = (float)acc[m][2 * p][j] * rs * swA;
            const float uv = (float)acc[m][2 * p + 1][j] * rs * swB;
            const float hv = uv / (1.f + exp2f(gv * -1.44269504f));
            C[(size_t)row * (N >> 1) + hbase + p * 16 + lr] = (OT)hv;
          }
        }
      }
    } else {
#pragma unroll
      for (int m = 0; m < 8; m++) {
#pragma unroll
        for (int j = 0; j < 4; j++) {
          const int row = em0 + wm * 128 + m * 16 + g * 4 + j;
          const float rs = rowscale[row] * swA;
#pragma unroll
          for (int n = 0; n < 4; n++) {
            const int col = en0 + wn * 64 + n * 16 + lr;
            C[(size_t)row * N + col] = (OT)((float)acc[m][n][j] * rs);
          }
        }
      }
    }
  }
#undef ITER
#undef INTERLEAVE
#undef READS
#undef MFMAS
#undef STAGE
#undef SETPTR
}

extern "C" void kernel_launch(void* const* d_in, const int* in_sizes, int n_in,
                              void* d_out, int out_size, void* d_ws, size_t ws_size,
                              hipStream_t stream) {
  const float* x  = (const float*)d_in[0];
  const float* wg = (const float*)d_in[1];
  const float* wu = (const float*)d_in[2];
  const float* wd = (const float*)d_in[3];
  float* out = (float*)d_out;
  char* ws = (char*)d_ws;

  double* dsum = (double*)(ws + OFF_DSUM);
  float* sx = (float*)(ws + OFF_SX);
  float* sh = (float*)(ws + OFF_SH);
  char* xq   = ws + OFF_XQ;
  char* wcat = ws + OFF_WCAT;  // [16384][2048] gate/up interleaved (16-row groups)
  char* wdq  = ws + OFF_WDQ;
  char* hq   = ws + OFF_HQ;    // full [8192][8192] int8

  // strip sizing: per row need 8192*2 B (h fp16); S multiple of 256
  size_t avail = ws_size > FIXED_END ? ws_size - FIXED_END : 0;
  int S = 256;
  for (int cand = 8192; cand >= 256; cand >>= 1) {
    if ((size_t)cand * 16384ull <= avail) { S = cand; break; }
  }
  _Float16* hbuf = (_Float16*)(ws + FIXED_END);

  hipMemsetAsync(ws, 0, 64, stream);

  const int n4 = NW / 4;
  k_wabs3<<<dim3(2048, 3), 256, 0, stream>>>(wg, wu, wd, dsum, n4);
  k_quant_w3<<<dim3(2048, 3), 256, 0, stream>>>(wg, wu, wd, wcat, wdq, dsum, n4);
  k_quant_x<<<TOK, 256, 0, stream>>>(x, xq, sx);

  for (int base = 0; base < TOK; base += S) {
    // h = sigmoid(x@wg^T) * (x@wu^T) computed in one persistent GEMM over
    // interleaved w_cat (N = 16384 weight cols -> 8192 fp16 h cols per row)
    k_gemm8<1, _Float16><<<256, 512, 0, stream>>>(
        xq + (size_t)base * DM, wcat, hbuf, sx + base,
        dsum + 0, dsum + 1, S, NGU, DM, (S / 256) * (NGU / 256));

    k_hquant<<<S, 256, 0, stream>>>(hbuf, hq + (size_t)base * DF, sh + base);
  }

  // single persistent down-projection GEMM over all rows (fp32 out)
  k_gemm8<0, float><<<256, 512, 0, stream>>>(
      hq, wdq, out, sh, dsum + 2, dsum + 2, TOK, DM, DF,
      (TOK / 256) * (DM / 256));
}

// Round 20
// 604.206 us; speedup vs baseline: 1.2269x; 1.0260x over previous
//
#include <hip/hip_runtime.h>
#include <math.h>

#define EPSQ 1e-5f
#define TOK 8192
#define DM 2048
#define DF 8192
#define NW (DM*DF)
#define NGU 16384   // interleaved gate/up weight rows (16-row groups)

typedef float f32x4 __attribute__((ext_vector_type(4)));
typedef int   int32x4 __attribute__((ext_vector_type(4)));
typedef char  i8x4 __attribute__((ext_vector_type(4)));
typedef char  i8x8 __attribute__((ext_vector_type(8)));
typedef _Float16 f16x8 __attribute__((ext_vector_type(8)));

// ---- fixed workspace layout (bytes) ----
#define OFF_DSUM 0ull                                // 3 doubles
#define OFF_SX   (4ull<<10)                          // 8192 f32
#define OFF_SH   (40ull<<10)                         // 8192 f32
#define OFF_XQ   (1ull<<20)                          // 16MB i8 [8192][2048]
#define OFF_WCAT (OFF_XQ  + (16ull<<20))             // 32MB i8 [16384][2048] gate/up interleaved
#define OFF_WDQ  (OFF_WCAT + (32ull<<20))            // 16MB i8 [2048][8192]
#define OFF_HQ   (OFF_WDQ + (16ull<<20))             // 64MB i8 [8192][8192]
#define FIXED_END (OFF_HQ + (64ull<<20))             // 129MB
// strip region (after FIXED_END): h fp16 [S][8192]

#define GLL(gp, lp) __builtin_amdgcn_global_load_lds( \
    (const __attribute__((address_space(1))) unsigned int*)(gp), \
    (__attribute__((address_space(3))) unsigned int*)(lp), 16, 0, 0)

// ---- |w| sums for all three weights (absmean scales), f64 totals ----
__global__ void k_wabs3(const float* __restrict__ w0, const float* __restrict__ w1,
                        const float* __restrict__ w2, double* __restrict__ dsum, int n4) {
  const float* w = blockIdx.y == 0 ? w0 : blockIdx.y == 1 ? w1 : w2;
  const f32x4* w4 = (const f32x4*)w;
  float s = 0.f;
  for (int i = blockIdx.x * blockDim.x + threadIdx.x; i < n4; i += gridDim.x * blockDim.x) {
    f32x4 v = w4[i];
    s += fabsf(v.x) + fabsf(v.y) + fabsf(v.z) + fabsf(v.w);
  }
  __shared__ float red[256];
  red[threadIdx.x] = s; __syncthreads();
  for (int o = 128; o > 0; o >>= 1) {
    if (threadIdx.x < o) red[threadIdx.x] += red[threadIdx.x + o];
    __syncthreads();
  }
  if (threadIdx.x == 0) atomicAdd(dsum + blockIdx.y, (double)red[0]);
}

// ---- ternary-quantize weights -> int8 {-1,0,1}.
// gate/up (y=0/1) write INTERLEAVED 16-row groups into wq_gu:
//   src row r -> R = 32*(r/16) + 16*y + (r%16); down (y=2) writes plain wq_d.
__global__ void k_quant_w3(const float* __restrict__ w0, const float* __restrict__ w1,
                           const float* __restrict__ w2, char* __restrict__ wq_gu,
                           char* __restrict__ wq_d, const double* __restrict__ dsum, int n4) {
  const int y = blockIdx.y;
  const float* w = y == 0 ? w0 : y == 1 ? w1 : w2;
  float scale = (float)(dsum[y] / (double)NW) + EPSQ;
  const f32x4* w4 = (const f32x4*)w;
  for (int i = blockIdx.x * blockDim.x + threadIdx.x; i < n4; i += gridDim.x * blockDim.x) {
    f32x4 v = w4[i];
    i8x4 o;
#pragma unroll
    for (int c = 0; c < 4; c++) {
      float q = rintf(v[c] / scale);
      q = fminf(1.f, fmaxf(-1.f, q));
      o[c] = (char)(int)q;
    }
    if (y < 2) {
      const int r = i >> 9, c4 = i & 511;        // 512 x f32x4 chunks per 2048-row
      const int R = ((r & ~15) << 1) + (y << 4) + (r & 15);
      *(i8x4*)&wq_gu[((size_t)R * 512 + c4) * 4] = o;
    } else {
      *(i8x4*)&wq_d[(size_t)i * 4] = o;
    }
  }
}

// ---- per-token int8 quantize x -> int8 + scale ----
__global__ void k_quant_x(const float* __restrict__ x, char* __restrict__ xq,
                          float* __restrict__ sx) {
  const int row = blockIdx.x;
  const int tid = threadIdx.x;
  const f32x4* xr = (const f32x4*)(x + (size_t)row * DM);
  f32x4 v0 = xr[tid * 2], v1 = xr[tid * 2 + 1];
  float m = 0.f;
#pragma unroll
  for (int c = 0; c < 4; c++) m = fmaxf(m, fmaxf(fabsf(v0[c]), fabsf(v1[c])));
  __shared__ float red[256];
  red[tid] = m; __syncthreads();
  for (int o = 128; o > 0; o >>= 1) {
    if (tid < o) red[tid] = fmaxf(red[tid], red[tid + o]);
    __syncthreads();
  }
  float sc = fmaxf(red[0], EPSQ) / 127.f;
  if (tid == 0) sx[row] = sc;
  i8x8 o;
#pragma unroll
  for (int c = 0; c < 4; c++) {
    float q0 = fminf(127.f, fmaxf(-128.f, rintf(v0[c] / sc)));
    float q1 = fminf(127.f, fmaxf(-128.f, rintf(v1[c] / sc)));
    o[c] = (char)(int)q0; o[c + 4] = (char)(int)q1;
  }
  *(i8x8*)&xq[(size_t)row * DM + tid * 8] = o;
}

// ---- row max + int8 quantize of h (fp16) ----
__global__ void k_hquant(const _Float16* __restrict__ h, char* __restrict__ hq,
                         float* __restrict__ sh) {
  const int row = blockIdx.x;
  const int tid = threadIdx.x;
  const f16x8* h8 = (const f16x8*)(h + (size_t)row * DF);
  float hv[32];
  float m = 0.f;
#pragma unroll
  for (int j = 0; j < 4; j++) {
    f16x8 v = h8[tid * 4 + j];
#pragma unroll
    for (int c = 0; c < 8; c++) {
      float f = (float)v[c];
      hv[j * 8 + c] = f;
      m = fmaxf(m, fabsf(f));
    }
  }
  __shared__ float red[256];
  red[tid] = m; __syncthreads();
  for (int o = 128; o > 0; o >>= 1) {
    if (tid < o) red[tid] = fmaxf(red[tid], red[tid + o]);
    __syncthreads();
  }
  float sc = fmaxf(red[0], EPSQ) / 127.f;
  if (tid == 0) sh[row] = sc;
#pragma unroll
  for (int jj = 0; jj < 4; jj++) {
    i8x8 o;
#pragma unroll
    for (int c = 0; c < 8; c++) {
      float q = fminf(127.f, fmaxf(-128.f, rintf(hv[jj * 8 + c] / sc)));
      o[c] = (char)(int)q;
    }
    *(i8x8*)&hq[(size_t)row * DF + tid * 32 + jj * 8] = o;
  }
}

// ---- PERSISTENT 256x256-tile i8 MFMA GEMM (16x16x64 MFMA; r17 K-loop).
//      4-deep BK=64 ring, frag double-buffer, counted vmcnt 8/4/0, T2 swizzle
//      via pre-swizzled GLL source (conflict-free), setprio+sched_group
//      interleave, persistent tile loop with next-prologue-before-epilogue.
//      NEW (r20): tile->block mapping for L2 locality:
//        lid = lidr*T + vt  -> a block's T tiles are CONSECUTIVE lids
//        (shares one B-panel across its tiles); 4x4 super-block lid->(m,n)
//        decomposition keeps per-16-lid working set (4 A + 4 B panels = 4MB)
//        ~= one XCD's L2. Bijective: gy,gx both multiples of 4.
// FUSE=0: C[row*N+col] = acc * rowscale[row] * swA           (OT = float)
// FUSE=1: weight cols are gate/up interleaved (16-col groups); epilogue
//         computes h = sigmoid(g)*u per pair and writes fp16 h at
//         h[row*(N/2) + (n0+wn*64)/2 + p*16 + lr]            (OT = _Float16)
template<int FUSE, typename OT>
__global__ __launch_bounds__(512, 2)
void k_gemm8(const char* __restrict__ A, const char* __restrict__ B,
             OT* __restrict__ C, const float* __restrict__ rowscale,
             const double* __restrict__ dsumA, const double* __restrict__ dsumB,
             int M, int N, int K, int nv) {
  __shared__ __align__(16) char sm[4][2][16384];

  const int tid = threadIdx.x;
  const int wv = tid >> 6;
  const int lane = tid & 63;
  const int wm = wv >> 2;
  const int wn = wv & 3;
  const int lr = lane & 15;
  const int g = lane >> 4;
  const int c3 = (lr >> 1) & 3;

  const int b = blockIdx.x;
  const int lidr = (b & 7) * 32 + (b >> 3);   // XCD swizzle within a round of 256
  const int gy = M >> 8;
  const int gy4 = gy >> 2;
  const int T = nv >> 8;                      // tiles per block

  const float swA = (float)(*dsumA / (double)NW) + EPSQ;
  const float swB = (float)(*dsumB / (double)NW) + EPSQ;

  const int srow = lane >> 2;
  const int sslot = (lane & 3) ^ ((lane >> 3) & 3);
  const int dst0 = (wv * 32) * 64 + lane * 16;
  const int dst1 = dst0 + 1024;
  const int NS = K >> 6;
  const int abase = (wm * 128 + lr) * 64 + ((g ^ c3) << 4);
  const int bbase = (wn * 64 + lr) * 64 + ((g ^ c3) << 4);

  int m0 = 0, n0 = 0;
  const char *gA0 = nullptr, *gA1 = nullptr, *gB0 = nullptr, *gB1 = nullptr;

#define SETPTR(vt) do { \
    const int lid_ = lidr * T + (vt); \
    const int sb_ = lid_ >> 4; \
    const int wi_ = lid_ & 15; \
    m0 = (((sb_ % gy4) << 2) + (wi_ & 3)) << 8; \
    n0 = (((sb_ / gy4) << 2) + (wi_ >> 2)) << 8; \
    gA0 = A + (size_t)(m0 + wv * 32 + srow) * K + sslot * 16; \
    gA1 = gA0 + (size_t)16 * K; \
    gB0 = B + (size_t)(n0 + wv * 32 + srow) * K + sslot * 16; \
    gB1 = gB0 + (size_t)16 * K; \
  } while (0)

#define STAGE(s) do { \
    const size_t ko_ = (size_t)(s) * 64; \
    char* pA_ = &sm[(s) & 3][0][0]; \
    char* pB_ = &sm[(s) & 3][1][0]; \
    GLL(gA0 + ko_, pA_ + dst0); \
    GLL(gA1 + ko_, pA_ + dst1); \
    GLL(gB0 + ko_, pB_ + dst0); \
    GLL(gB1 + ko_, pB_ + dst1); \
  } while (0)

#define READS(NA, NB, slot_) do { \
    const char* smA_ = &sm[(slot_)][0][0]; \
    const char* smB_ = &sm[(slot_)][1][0]; \
    _Pragma("unroll") \
    for (int n = 0; n < 4; n++) NB[n] = *(const int32x4*)&smB_[bbase + n * 1024]; \
    _Pragma("unroll") \
    for (int m = 0; m < 8; m++) NA[m] = *(const int32x4*)&smA_[abase + m * 1024]; \
  } while (0)

#define MFMAS(CA, CB) do { \
    _Pragma("unroll") \
    for (int m = 0; m < 8; m++) \
      _Pragma("unroll") \
      for (int n = 0; n < 4; n++) \
        acc[m][n] = __builtin_amdgcn_mfma_i32_16x16x64_i8(CA[m], CB[n], acc[m][n], 0, 0, 0); \
  } while (0)

#define INTERLEAVE() do { \
    _Pragma("unroll") \
    for (int gg = 0; gg < 6; gg++) { \
      __builtin_amdgcn_sched_group_barrier(0x100, 2, 0); \
      __builtin_amdgcn_sched_group_barrier(0x008, 5, 0); \
    } \
    __builtin_amdgcn_sched_group_barrier(0x008, 2, 0); \
  } while (0)

#define ITER(sv, CA, CB, NA, NB) do { \
    const int s_ = (sv); \
    const int ahead_ = NS - 1 - s_; \
    if (ahead_ >= 3) { \
      STAGE(s_ + 3); \
      asm volatile("s_waitcnt vmcnt(8)" ::: "memory"); \
    } else if (ahead_ == 2) { \
      asm volatile("s_waitcnt vmcnt(4)" ::: "memory"); \
    } else { \
      asm volatile("s_waitcnt vmcnt(0)" ::: "memory"); \
    } \
    asm volatile("s_waitcnt lgkmcnt(0)" ::: "memory"); \
    __builtin_amdgcn_sched_barrier(0); \
    __builtin_amdgcn_s_barrier(); \
    __builtin_amdgcn_s_setprio(1); \
    READS(NA, NB, (s_ + 1) & 3); \
    MFMAS(CA, CB); \
    INTERLEAVE(); \
    __builtin_amdgcn_s_setprio(0); \
  } while (0)

  int32x4 acc[8][4];
  const int32x4 z4 = {0, 0, 0, 0};
  int32x4 curA[8], curB[4], nxtA[8], nxtB[4];

  SETPTR(0);
  STAGE(0); STAGE(1); STAGE(2);

  for (int vt = 0; vt < T; ++vt) {
    const int em0 = m0, en0 = n0;   // epilogue coords for THIS tile

#pragma unroll
    for (int m = 0; m < 8; m++)
#pragma unroll
      for (int n = 0; n < 4; n++) acc[m][n] = z4;

    asm volatile("s_waitcnt vmcnt(8)" ::: "memory");
    __builtin_amdgcn_s_barrier();
    READS(curA, curB, 0);

    for (int s = 0; s + 1 < NS - 1; s += 2) {
      ITER(s, curA, curB, nxtA, nxtB);
      ITER(s + 1, nxtA, nxtB, curA, curB);
    }
    ITER(NS - 2, curA, curB, nxtA, nxtB);

    asm volatile("s_waitcnt lgkmcnt(0)" ::: "memory");
    __builtin_amdgcn_sched_barrier(0);
    __builtin_amdgcn_s_setprio(1);
    MFMAS(nxtA, nxtB);
    __builtin_amdgcn_s_setprio(0);

    // issue NEXT tile's prologue stages before the epilogue (latency hiding).
    // LDS hazard audit: slots 0,1,2 last read >=1 barrier ago (lgkm-drained);
    // slot 3 (still in flight for final MFMAS regs) is untouched.
    if (vt + 1 < T) {
      SETPTR(vt + 1);
      STAGE(0); STAGE(1); STAGE(2);
    }

    // epilogue: C/D layout col = lane&15, row = (lane>>4)*4 + j
    if constexpr (FUSE) {
      const int hbase = (en0 + wn * 64) >> 1;
#pragma unroll
      for (int m = 0; m < 8; m++) {
#pragma unroll
        for (int j = 0; j < 4; j++) {
          const int row = em0 + wm * 128 + m * 16 + g * 4 + j;
          const float rs = rowscale[row];
#pragma unroll
          for (int p = 0; p < 2; p++) {
            const float gv = (float)acc[m][2 * p][j] * rs * swA;
            const float uv = (float)acc[m][2 * p + 1][j] * rs * swB;
            const float hv = uv / (1.f + exp2f(gv * -1.44269504f));
            C[(size_t)row * (N >> 1) + hbase + p * 16 + lr] = (OT)hv;
          }
        }
      }
    } else {
#pragma unroll
      for (int m = 0; m < 8; m++) {
#pragma unroll
        for (int j = 0; j < 4; j++) {
          const int row = em0 + wm * 128 + m * 16 + g * 4 + j;
          const float rs = rowscale[row] * swA;
#pragma unroll
          for (int n = 0; n < 4; n++) {
            const int col = en0 + wn * 64 + n * 16 + lr;
            C[(size_t)row * N + col] = (OT)((float)acc[m][n][j] * rs);
          }
        }
      }
    }
  }
#undef ITER
#undef INTERLEAVE
#undef READS
#undef MFMAS
#undef STAGE
#undef SETPTR
}

extern "C" void kernel_launch(void* const* d_in, const int* in_sizes, int n_in,
                              void* d_out, int out_size, void* d_ws, size_t ws_size,
                              hipStream_t stream) {
  const float* x  = (const float*)d_in[0];
  const float* wg = (const float*)d_in[1];
  const float* wu = (const float*)d_in[2];
  const float* wd = (const float*)d_in[3];
  float* out = (float*)d_out;
  char* ws = (char*)d_ws;

  double* dsum = (double*)(ws + OFF_DSUM);
  float* sx = (float*)(ws + OFF_SX);
  float* sh = (float*)(ws + OFF_SH);
  char* xq   = ws + OFF_XQ;
  char* wcat = ws + OFF_WCAT;  // [16384][2048] gate/up interleaved (16-row groups)
  char* wdq  = ws + OFF_WDQ;
  char* hq   = ws + OFF_HQ;    // full [8192][8192] int8

  // strip sizing: per row need 8192*2 B (h fp16); S multiple of 256
  size_t avail = ws_size > FIXED_END ? ws_size - FIXED_END : 0;
  int S = 256;
  for (int cand = 8192; cand >= 256; cand >>= 1) {
    if ((size_t)cand * 16384ull <= avail) { S = cand; break; }
  }
  _Float16* hbuf = (_Float16*)(ws + FIXED_END);

  hipMemsetAsync(ws, 0, 64, stream);

  const int n4 = NW / 4;
  k_wabs3<<<dim3(2048, 3), 256, 0, stream>>>(wg, wu, wd, dsum, n4);
  k_quant_w3<<<dim3(2048, 3), 256, 0, stream>>>(wg, wu, wd, wcat, wdq, dsum, n4);
  k_quant_x<<<TOK, 256, 0, stream>>>(x, xq, sx);

  for (int base = 0; base < TOK; base += S) {
    // h = sigmoid(x@wg^T) * (x@wu^T) computed in one persistent GEMM over
    // interleaved w_cat (N = 16384 weight cols -> 8192 fp16 h cols per row)
    k_gemm8<1, _Float16><<<256, 512, 0, stream>>>(
        xq + (size_t)base * DM, wcat, hbuf, sx + base,
        dsum + 0, dsum + 1, S, NGU, DM, (S / 256) * (NGU / 256));

    k_hquant<<<S, 256, 0, stream>>>(hbuf, hq + (size_t)base * DF, sh + base);
  }

  // single persistent down-projection GEMM over all rows (fp32 out)
  k_gemm8<0, float><<<256, 512, 0, stream>>>(
      hq, wdq, out, sh, dsum + 2, dsum + 2, TOK, DM, DF,
      (TOK / 256) * (DM / 256));
}